// Round 6
// baseline (1277.037 us; speedup 1.0000x reference)
//
#include <hip/hip_runtime.h>
#include <hip/hip_bf16.h>
#include <cstdint>

#define B_ 256
#define T_ 512
#define F_ 128
#define H_ 128
#define G3_ 384
#define R_ 8
#define K_ 64

typedef __attribute__((ext_vector_type(8))) short short8_t;
typedef __attribute__((ext_vector_type(4))) float f32x4;

__device__ __forceinline__ float sigm(float x) { return 1.f / (1.f + __expf(-x)); }
__device__ __forceinline__ float tanh_f(float x) { return 1.f - 2.f / (1.f + __expf(2.f * x)); }
// RNE float->bf16 (finite inputs)
__device__ __forceinline__ unsigned short f2bf(float f) {
    uint32_t u = __builtin_bit_cast(uint32_t, f);
    return (unsigned short)((u + 0x7FFFu + ((u >> 16) & 1u)) >> 16);
}
__device__ __forceinline__ short8_t pack8(float4 a, float4 b) {
    short8_t v;
    v[0] = (short)f2bf(a.x); v[1] = (short)f2bf(a.y);
    v[2] = (short)f2bf(a.z); v[3] = (short)f2bf(a.w);
    v[4] = (short)f2bf(b.x); v[5] = (short)f2bf(b.y);
    v[6] = (short)f2bf(b.z); v[7] = (short)f2bf(b.w);
    return v;
}

// Force 8 floats to be homed in arch VGPRs at this program point.
#define PIN8(a)                                                              \
    asm("" : "+v"(a[0]), "+v"(a[1]), "+v"(a[2]), "+v"(a[3]),                 \
             "+v"(a[4]), "+v"(a[5]), "+v"(a[6]), "+v"(a[7]))

// MFMA GEMM: C[m][n] = sum_k A[m][k]*W[n][k] + bias[n], row-major C.
// M = B*T (rows of A, 128 wide), N = 384. Block = 128 M x 384 N, 8 waves.
// W fragments (bf16) persist in VGPRs. A tile staged fp32->bf16 into
// XOR-swizzled LDS. fp32 accumulate.
__global__ __launch_bounds__(512, 2) void gemm_gi_mfma(const float* __restrict__ A,
                                                       const float* __restrict__ W,
                                                       const float* __restrict__ bias,
                                                       float* __restrict__ C)
{
    __shared__ alignas(16) unsigned short A_lds[128 * 128];  // bf16, swizzled

    const int tid = threadIdx.x;
    const int wv = tid >> 6, lane = tid & 63;
    const int lc = lane & 15, lg = lane >> 4;
    const size_t m0 = (size_t)blockIdx.x * 128;

    // ---- B-fragments: wave wv covers n = 48*wv + 16u + lc, u = 0..2
    short8_t bf[3][4];
    float bi[3];
    #pragma unroll
    for (int u = 0; u < 3; ++u) {
        const int n = 48 * wv + 16 * u + lc;
        bi[u] = bias[n];
        #pragma unroll
        for (int ks = 0; ks < 4; ++ks) {
            const float4* wp = (const float4*)(W + (size_t)n * 128 + ks * 32 + lg * 8);
            bf[u][ks] = pack8(wp[0], wp[1]);
        }
    }

    // ---- stage A tile: thread -> row m = tid>>2, k-range (tid&3)*32
    {
        const int m = tid >> 2, kq = tid & 3;
        const float4* ap = (const float4*)(A + (m0 + m) * 128 + kq * 32);
        float4 v0 = ap[0], v1 = ap[1], v2 = ap[2], v3 = ap[3];
        float4 v4 = ap[4], v5 = ap[5], v6 = ap[6], v7 = ap[7];
        char* base = (char*)A_lds;
        const int bb = m * 256 + kq * 64, sw = (m & 7) << 4;
        *(short8_t*)(base + ((bb +  0) ^ sw)) = pack8(v0, v1);
        *(short8_t*)(base + ((bb + 16) ^ sw)) = pack8(v2, v3);
        *(short8_t*)(base + ((bb + 32) ^ sw)) = pack8(v4, v5);
        *(short8_t*)(base + ((bb + 48) ^ sw)) = pack8(v6, v7);
    }
    __syncthreads();

    // ---- 8 m-tiles x (3 n-tiles x 4 k) MFMAs
    const char* Ab = (const char*)A_lds;
    #pragma unroll 2
    for (int mt = 0; mt < 8; ++mt) {
        short8_t af0 = *(const short8_t*)(Ab + (((mt * 16 + lc) * 256 +  0 + lg * 16) ^ ((lc & 7) << 4)));
        short8_t af1 = *(const short8_t*)(Ab + (((mt * 16 + lc) * 256 + 64 + lg * 16) ^ ((lc & 7) << 4)));
        short8_t af2 = *(const short8_t*)(Ab + (((mt * 16 + lc) * 256 + 128 + lg * 16) ^ ((lc & 7) << 4)));
        short8_t af3 = *(const short8_t*)(Ab + (((mt * 16 + lc) * 256 + 192 + lg * 16) ^ ((lc & 7) << 4)));
        f32x4 a0 = {0.f, 0.f, 0.f, 0.f}, a1 = a0, a2 = a0;
        a0 = __builtin_amdgcn_mfma_f32_16x16x32_bf16(af0, bf[0][0], a0, 0, 0, 0);
        a1 = __builtin_amdgcn_mfma_f32_16x16x32_bf16(af0, bf[1][0], a1, 0, 0, 0);
        a2 = __builtin_amdgcn_mfma_f32_16x16x32_bf16(af0, bf[2][0], a2, 0, 0, 0);
        a0 = __builtin_amdgcn_mfma_f32_16x16x32_bf16(af1, bf[0][1], a0, 0, 0, 0);
        a1 = __builtin_amdgcn_mfma_f32_16x16x32_bf16(af1, bf[1][1], a1, 0, 0, 0);
        a2 = __builtin_amdgcn_mfma_f32_16x16x32_bf16(af1, bf[2][1], a2, 0, 0, 0);
        a0 = __builtin_amdgcn_mfma_f32_16x16x32_bf16(af2, bf[0][2], a0, 0, 0, 0);
        a1 = __builtin_amdgcn_mfma_f32_16x16x32_bf16(af2, bf[1][2], a1, 0, 0, 0);
        a2 = __builtin_amdgcn_mfma_f32_16x16x32_bf16(af2, bf[2][2], a2, 0, 0, 0);
        a0 = __builtin_amdgcn_mfma_f32_16x16x32_bf16(af3, bf[0][3], a0, 0, 0, 0);
        a1 = __builtin_amdgcn_mfma_f32_16x16x32_bf16(af3, bf[1][3], a1, 0, 0, 0);
        a2 = __builtin_amdgcn_mfma_f32_16x16x32_bf16(af3, bf[2][3], a2, 0, 0, 0);
        // D: row = 4*lg + r, col = 48*wv + 16u + lc
        #pragma unroll
        for (int r = 0; r < 4; ++r) {
            float* cp = C + (m0 + mt * 16 + 4 * lg + r) * G3_ + 48 * wv + lc;
            cp[0]  = a0[r] + bi[0];
            cp[16] = a1[r] + bi[1];
            cp[32] = a2[r] + bi[2];
        }
    }
}

// One block (512 threads, 8 waves) per batch element.
// Thread: j = 16*(tid>>6) + (lane>>2); k-chunk s = lane&3 covers [32s,32s+32).
// 96 FMAs/thread; reduce over s via shfl_xor 1/2 (quad-perm DPP).
// h double-buffered in LDS [4][36] (conflict-free broadcast).
// gi prefetched FOUR steps ahead (named register sets).
// ONE raw s_barrier per step, lgkm-only drain.
// NEW: weight arrays PINNED to arch VGPRs once per step (kills the
// AGPR-parking / per-use copy inflation seen in rounds 2/3/5).
__global__ __launch_bounds__(512, 2) void gru_seq(const float* __restrict__ gi,
                                                  const float* __restrict__ Whh,
                                                  const float* __restrict__ bhh,
                                                  float* __restrict__ hout)
{
    __shared__ alignas(16) float hbuf[2][4][36];

    const int tid = threadIdx.x;
    const int b = blockIdx.x;
    const int w = tid >> 6, lane = tid & 63;
    const int j = 16 * w + (lane >> 2);
    const int s = lane & 3;
    const bool fin = (s == 0);

    // per-thread weights: rows j (r), 128+j (z), 256+j (n), cols [32s,32s+32)
    float wr[32], wz[32], wn[32];
    {
        const float4* p0 = (const float4*)(Whh + (size_t)j * 128 + s * 32);
        const float4* p1 = (const float4*)(Whh + (size_t)(128 + j) * 128 + s * 32);
        const float4* p2 = (const float4*)(Whh + (size_t)(256 + j) * 128 + s * 32);
        #pragma unroll
        for (int q = 0; q < 8; ++q) {
            float4 v0 = p0[q], v1 = p1[q], v2 = p2[q];
            wr[4*q+0]=v0.x; wr[4*q+1]=v0.y; wr[4*q+2]=v0.z; wr[4*q+3]=v0.w;
            wz[4*q+0]=v1.x; wz[4*q+1]=v1.y; wz[4*q+2]=v1.z; wz[4*q+3]=v1.w;
            wn[4*q+0]=v2.x; wn[4*q+1]=v2.y; wn[4*q+2]=v2.z; wn[4*q+3]=v2.w;
        }
    }
    const float br = bhh[j], bz = bhh[128 + j], bn = bhh[256 + j];

    if (tid < H_) hbuf[0][tid >> 5][tid & 31] = 0.f;
    __syncthreads();

    const float* gip = gi + (size_t)b * T_ * G3_ + j;
    float* hop = hout + (size_t)b * T_ * H_ + j;

    // 4-deep gi prefetch (finalize lanes only), named sets for static indexing
    float g0[3], g1[3], g2[3], g3[3];
    if (fin) {
        #pragma unroll
        for (int u = 0; u < 3; ++u) {
            g0[u] = gip[0 * G3_ + 128 * u];
            g1[u] = gip[1 * G3_ + 128 * u];
            g2[u] = gip[2 * G3_ + 128 * u];
            g3[u] = gip[3 * G3_ + 128 * u];
        }
    }
    float hprev = 0.f;

    auto step = [&](int t, float (&gc)[3]) {
        // Pin all long-lived weights into arch VGPRs at step start: the
        // allocator must home them in v-regs, not park them in AGPRs.
        PIN8((&wr[0])); PIN8((&wr[8])); PIN8((&wr[16])); PIN8((&wr[24]));
        PIN8((&wz[0])); PIN8((&wz[8])); PIN8((&wz[16])); PIN8((&wz[24]));
        PIN8((&wn[0])); PIN8((&wn[8])); PIN8((&wn[16])); PIN8((&wn[24]));

        const int p = t & 1;
        const float4* hv = (const float4*)(&hbuf[p][s][0]);
        float pr = 0.f, pz = 0.f, pn = 0.f;
        #pragma unroll
        for (int q = 0; q < 8; ++q) {
            float4 h4 = hv[q];
            float hh[4] = {h4.x, h4.y, h4.z, h4.w};
            #pragma unroll
            for (int e = 0; e < 4; ++e) {
                pr += wr[4*q+e] * hh[e];
                pz += wz[4*q+e] * hh[e];
                pn += wn[4*q+e] * hh[e];
            }
        }
        // reduce over 4 k-chunks: quad-perm DPP (VALU pipe)
        pr += __shfl_xor(pr, 1); pr += __shfl_xor(pr, 2);
        pz += __shfl_xor(pz, 1); pz += __shfl_xor(pz, 2);
        pn += __shfl_xor(pn, 1); pn += __shfl_xor(pn, 2);

        if (fin) {
            float r  = sigm(gc[0] + pr + br);
            float z  = sigm(gc[1] + pz + bz);
            float nn = tanh_f(gc[2] + r * (pn + bn));
            float h  = (1.f - z) * nn + z * hprev;
            hprev = h;
            hbuf[p ^ 1][j >> 5][j & 31] = h;
            hop[(size_t)t * H_] = h;                     // fire-and-forget
            // refill this set for t+4
            int tn = (t + 4 < T_) ? t + 4 : T_ - 1;
            const float* gp = gip + (size_t)tn * G3_;
            gc[0] = gp[0]; gc[1] = gp[128]; gc[2] = gp[256];
        }
        // LDS-only drain + raw barrier (global ops stay in flight)
        asm volatile("s_waitcnt lgkmcnt(0)" ::: "memory");
        __builtin_amdgcn_s_barrier();
    };

    for (int t = 0; t < T_; t += 4) {
        step(t + 0, g0);
        step(t + 1, g1);
        step(t + 2, g2);
        step(t + 3, g3);
    }
}

// One wave per sample: a = h2·W1[reg] + b1[reg]; SiLU; corr = a·W2[reg] + b2[reg]
__global__ __launch_bounds__(256) void head_k(const float* __restrict__ h2,
                                              const float* __restrict__ x,
                                              const int* __restrict__ regime,
                                              const float* __restrict__ W1,
                                              const float* __restrict__ b1,
                                              const float* __restrict__ W2,
                                              const float* __restrict__ b2,
                                              const float* __restrict__ lag_scale,
                                              const float* __restrict__ lag_bias,
                                              float* __restrict__ out)
{
    __shared__ alignas(16) float hrow[4][128];
    const int tid = threadIdx.x;
    const int wv = tid >> 6, lane = tid & 63;
    const size_t s = (size_t)blockIdx.x * 4 + wv;
    const int reg = regime[s];

    if (lane < 32)
        ((float4*)hrow[wv])[lane] = ((const float4*)(h2 + s * H_))[lane];
    __syncthreads();

    float acc = b1[reg * K_ + lane];
    const float* Wp = W1 + (size_t)reg * H_ * K_ + lane;
    const float4* h4p = (const float4*)hrow[wv];
    #pragma unroll
    for (int q = 0; q < 32; ++q) {
        float4 h4 = h4p[q];
        acc += h4.x * Wp[(4 * q + 0) * K_];
        acc += h4.y * Wp[(4 * q + 1) * K_];
        acc += h4.z * Wp[(4 * q + 2) * K_];
        acc += h4.w * Wp[(4 * q + 3) * K_];
    }
    float silu = acc * sigm(acc);
    float v = silu * W2[reg * K_ + lane];
    #pragma unroll
    for (int m = 1; m < 64; m <<= 1) v += __shfl_xor(v, m);
    if (lane == 0) {
        float lag = lag_scale[0] * x[s * F_] + lag_bias[0];
        out[s] = lag + v + b2[reg];
    }
}

extern "C" void kernel_launch(void* const* d_in, const int* in_sizes, int n_in,
                              void* d_out, int out_size, void* d_ws, size_t ws_size,
                              hipStream_t stream) {
    const float* x         = (const float*)d_in[0];
    const int*   regime    = (const int*)d_in[1];
    const float* lag_scale = (const float*)d_in[2];
    const float* lag_bias  = (const float*)d_in[3];
    const float* Wih0      = (const float*)d_in[4];
    const float* Whh0      = (const float*)d_in[5];
    const float* bih0      = (const float*)d_in[6];
    const float* bhh0      = (const float*)d_in[7];
    const float* Wih1      = (const float*)d_in[8];
    const float* Whh1      = (const float*)d_in[9];
    const float* bih1      = (const float*)d_in[10];
    const float* bhh1      = (const float*)d_in[11];
    const float* W1        = (const float*)d_in[12];
    const float* b1        = (const float*)d_in[13];
    const float* W2        = (const float*)d_in[14];
    const float* b2        = (const float*)d_in[15];
    float* out = (float*)d_out;

    const size_t NT = (size_t)B_ * T_;               // 131072
    const size_t need = NT * G3_ * 4 + NT * H_ * 4;  // 256 MiB
    if (ws_size < need) {
        hipMemsetAsync(d_out, 0x7F, (size_t)out_size * 4, stream);
        return;
    }
    float* gi = (float*)d_ws;
    float* hb = gi + NT * G3_;                       // h1, then reused as h2

    const int gblocks = (int)(NT / 128);             // 1024
    gemm_gi_mfma<<<gblocks, 512, 0, stream>>>(x, Wih0, bih0, gi);
    gru_seq<<<B_, 512, 0, stream>>>(gi, Whh0, bhh0, hb);
    gemm_gi_mfma<<<gblocks, 512, 0, stream>>>(hb, Wih1, bih1, gi);
    gru_seq<<<B_, 512, 0, stream>>>(gi, Whh1, bhh1, hb);
    head_k<<<(int)(NT / 4), 256, 0, stream>>>(hb, x, regime, W1, b1, W2, b2,
                                              lag_scale, lag_bias, out);
}

// Round 8
// 975.305 us; speedup vs baseline: 1.3094x; 1.3094x over previous
//
#include <hip/hip_runtime.h>
#include <hip/hip_bf16.h>
#include <cstdint>

#define B_ 256
#define T_ 512
#define F_ 128
#define H_ 128
#define G3_ 384
#define R_ 8
#define K_ 64

typedef __attribute__((ext_vector_type(8))) short short8_t;
typedef __attribute__((ext_vector_type(4))) float f32x4;
typedef __attribute__((ext_vector_type(2))) float f32x2;

__device__ __forceinline__ float sigm(float x) { return 1.f / (1.f + __expf(-x)); }
__device__ __forceinline__ float tanh_f(float x) { return 1.f - 2.f / (1.f + __expf(2.f * x)); }
// RNE float->bf16 (finite inputs)
__device__ __forceinline__ unsigned short f2bf(float f) {
    uint32_t u = __builtin_bit_cast(uint32_t, f);
    return (unsigned short)((u + 0x7FFFu + ((u >> 16) & 1u)) >> 16);
}
__device__ __forceinline__ short8_t pack8(float4 a, float4 b) {
    short8_t v;
    v[0] = (short)f2bf(a.x); v[1] = (short)f2bf(a.y);
    v[2] = (short)f2bf(a.z); v[3] = (short)f2bf(a.w);
    v[4] = (short)f2bf(b.x); v[5] = (short)f2bf(b.y);
    v[6] = (short)f2bf(b.z); v[7] = (short)f2bf(b.w);
    return v;
}

// MFMA GEMM: C[m][n] = sum_k A[m][k]*W[n][k] + bias[n], row-major C.
// M = B*T, N = 384. Block = 128 M x 384 N, 8 waves. W fragments (bf16)
// persist in VGPRs. A staged fp32->bf16 in XOR-swizzled LDS. fp32 accum.
__global__ __launch_bounds__(512, 2) void gemm_gi_mfma(const float* __restrict__ A,
                                                       const float* __restrict__ W,
                                                       const float* __restrict__ bias,
                                                       float* __restrict__ C)
{
    __shared__ alignas(16) unsigned short A_lds[128 * 128];  // bf16, swizzled

    const int tid = threadIdx.x;
    const int wv = tid >> 6, lane = tid & 63;
    const int lc = lane & 15, lg = lane >> 4;
    const size_t m0 = (size_t)blockIdx.x * 128;

    short8_t bf[3][4];
    float bi[3];
    #pragma unroll
    for (int u = 0; u < 3; ++u) {
        const int n = 48 * wv + 16 * u + lc;
        bi[u] = bias[n];
        #pragma unroll
        for (int ks = 0; ks < 4; ++ks) {
            const float4* wp = (const float4*)(W + (size_t)n * 128 + ks * 32 + lg * 8);
            bf[u][ks] = pack8(wp[0], wp[1]);
        }
    }

    {
        const int m = tid >> 2, kq = tid & 3;
        const float4* ap = (const float4*)(A + (m0 + m) * 128 + kq * 32);
        float4 v0 = ap[0], v1 = ap[1], v2 = ap[2], v3 = ap[3];
        float4 v4 = ap[4], v5 = ap[5], v6 = ap[6], v7 = ap[7];
        char* base = (char*)A_lds;
        const int bb = m * 256 + kq * 64, sw = (m & 7) << 4;
        *(short8_t*)(base + ((bb +  0) ^ sw)) = pack8(v0, v1);
        *(short8_t*)(base + ((bb + 16) ^ sw)) = pack8(v2, v3);
        *(short8_t*)(base + ((bb + 32) ^ sw)) = pack8(v4, v5);
        *(short8_t*)(base + ((bb + 48) ^ sw)) = pack8(v6, v7);
    }
    __syncthreads();

    const char* Ab = (const char*)A_lds;
    #pragma unroll 2
    for (int mt = 0; mt < 8; ++mt) {
        short8_t af0 = *(const short8_t*)(Ab + (((mt * 16 + lc) * 256 +  0 + lg * 16) ^ ((lc & 7) << 4)));
        short8_t af1 = *(const short8_t*)(Ab + (((mt * 16 + lc) * 256 + 64 + lg * 16) ^ ((lc & 7) << 4)));
        short8_t af2 = *(const short8_t*)(Ab + (((mt * 16 + lc) * 256 + 128 + lg * 16) ^ ((lc & 7) << 4)));
        short8_t af3 = *(const short8_t*)(Ab + (((mt * 16 + lc) * 256 + 192 + lg * 16) ^ ((lc & 7) << 4)));
        f32x4 a0 = {0.f, 0.f, 0.f, 0.f}, a1 = a0, a2 = a0;
        a0 = __builtin_amdgcn_mfma_f32_16x16x32_bf16(af0, bf[0][0], a0, 0, 0, 0);
        a1 = __builtin_amdgcn_mfma_f32_16x16x32_bf16(af0, bf[1][0], a1, 0, 0, 0);
        a2 = __builtin_amdgcn_mfma_f32_16x16x32_bf16(af0, bf[2][0], a2, 0, 0, 0);
        a0 = __builtin_amdgcn_mfma_f32_16x16x32_bf16(af1, bf[0][1], a0, 0, 0, 0);
        a1 = __builtin_amdgcn_mfma_f32_16x16x32_bf16(af1, bf[1][1], a1, 0, 0, 0);
        a2 = __builtin_amdgcn_mfma_f32_16x16x32_bf16(af1, bf[2][1], a2, 0, 0, 0);
        a0 = __builtin_amdgcn_mfma_f32_16x16x32_bf16(af2, bf[0][2], a0, 0, 0, 0);
        a1 = __builtin_amdgcn_mfma_f32_16x16x32_bf16(af2, bf[1][2], a1, 0, 0, 0);
        a2 = __builtin_amdgcn_mfma_f32_16x16x32_bf16(af2, bf[2][2], a2, 0, 0, 0);
        a0 = __builtin_amdgcn_mfma_f32_16x16x32_bf16(af3, bf[0][3], a0, 0, 0, 0);
        a1 = __builtin_amdgcn_mfma_f32_16x16x32_bf16(af3, bf[1][3], a1, 0, 0, 0);
        a2 = __builtin_amdgcn_mfma_f32_16x16x32_bf16(af3, bf[2][3], a2, 0, 0, 0);
        #pragma unroll
        for (int r = 0; r < 4; ++r) {
            float* cp = C + (m0 + mt * 16 + 4 * lg + r) * G3_ + 48 * wv + lc;
            cp[0]  = a0[r] + bi[0];
            cp[16] = a1[r] + bi[1];
            cp[32] = a2[r] + bi[2];
        }
    }
}

// One block (512 threads, 8 waves) per batch element.
// Thread: j = 16*(tid>>6) + (lane>>2); k-chunk s = lane&3 covers [32s,32s+32).
// Matvec as f32x2 packed ops (target: v_pk_fma_f32 -> halves FMA issue count;
// if the backend declines, degrades to round-5 scalar FMAs exactly).
// Two fp32 accumulators per gate (shorter dep chains). h double-buffered in
// LDS [4][36] (conflict-free broadcast). gi prefetched FOUR steps ahead.
// ONE raw s_barrier per step, lgkm-only drain.
__global__ __launch_bounds__(512, 2) void gru_seq(const float* __restrict__ gi,
                                                  const float* __restrict__ Whh,
                                                  const float* __restrict__ bhh,
                                                  float* __restrict__ hout)
{
    __shared__ alignas(16) float hbuf[2][4][36];

    const int tid = threadIdx.x;
    const int b = blockIdx.x;
    const int w = tid >> 6, lane = tid & 63;
    const int j = 16 * w + (lane >> 2);
    const int s = lane & 3;
    const bool fin = (s == 0);

    // per-thread weights as fp32 PAIRS: rows j, 128+j, 256+j; cols [32s,32s+32)
    f32x2 wr2[16], wz2[16], wn2[16];
    {
        const float4* p0 = (const float4*)(Whh + (size_t)j * 128 + s * 32);
        const float4* p1 = (const float4*)(Whh + (size_t)(128 + j) * 128 + s * 32);
        const float4* p2 = (const float4*)(Whh + (size_t)(256 + j) * 128 + s * 32);
        #pragma unroll
        for (int q = 0; q < 8; ++q) {
            float4 v0 = p0[q], v1 = p1[q], v2 = p2[q];
            wr2[2*q]   = f32x2{v0.x, v0.y};
            wr2[2*q+1] = f32x2{v0.z, v0.w};
            wz2[2*q]   = f32x2{v1.x, v1.y};
            wz2[2*q+1] = f32x2{v1.z, v1.w};
            wn2[2*q]   = f32x2{v2.x, v2.y};
            wn2[2*q+1] = f32x2{v2.z, v2.w};
        }
    }
    const float br = bhh[j], bz = bhh[128 + j], bn = bhh[256 + j];

    if (tid < H_) hbuf[0][tid >> 5][tid & 31] = 0.f;
    __syncthreads();

    const float* gip = gi + (size_t)b * T_ * G3_ + j;
    float* hop = hout + (size_t)b * T_ * H_ + j;

    // 4-deep gi prefetch (finalize lanes only), named sets for static indexing
    float g0[3], g1[3], g2[3], g3[3];
    if (fin) {
        #pragma unroll
        for (int u = 0; u < 3; ++u) {
            g0[u] = gip[0 * G3_ + 128 * u];
            g1[u] = gip[1 * G3_ + 128 * u];
            g2[u] = gip[2 * G3_ + 128 * u];
            g3[u] = gip[3 * G3_ + 128 * u];
        }
    }
    float hprev = 0.f;

    auto step = [&](int t, float (&gc)[3]) {
        const int p = t & 1;
        const float4* hv = (const float4*)(&hbuf[p][s][0]);
        f32x2 pr2 = {0.f, 0.f}, pz2 = pr2, pn2 = pr2;
        #pragma unroll
        for (int q = 0; q < 8; ++q) {
            float4 h4 = hv[q];
            f32x2 ha = {h4.x, h4.y};
            f32x2 hb = {h4.z, h4.w};
            pr2 += wr2[2*q] * ha;  pr2 += wr2[2*q+1] * hb;
            pz2 += wz2[2*q] * ha;  pz2 += wz2[2*q+1] * hb;
            pn2 += wn2[2*q] * ha;  pn2 += wn2[2*q+1] * hb;
        }
        float pr = pr2[0] + pr2[1];
        float pz = pz2[0] + pz2[1];
        float pn = pn2[0] + pn2[1];
        // reduce over 4 k-chunks: quad-perm DPP (VALU pipe)
        pr += __shfl_xor(pr, 1); pr += __shfl_xor(pr, 2);
        pz += __shfl_xor(pz, 1); pz += __shfl_xor(pz, 2);
        pn += __shfl_xor(pn, 1); pn += __shfl_xor(pn, 2);

        if (fin) {
            float r  = sigm(gc[0] + pr + br);
            float z  = sigm(gc[1] + pz + bz);
            float nn = tanh_f(gc[2] + r * (pn + bn));
            float h  = (1.f - z) * nn + z * hprev;
            hprev = h;
            hbuf[p ^ 1][j >> 5][j & 31] = h;
            hop[(size_t)t * H_] = h;                     // fire-and-forget
            // refill this set for t+4
            int tn = (t + 4 < T_) ? t + 4 : T_ - 1;
            const float* gp = gip + (size_t)tn * G3_;
            gc[0] = gp[0]; gc[1] = gp[128]; gc[2] = gp[256];
        }
        // LDS-only drain + raw barrier (global ops stay in flight)
        asm volatile("s_waitcnt lgkmcnt(0)" ::: "memory");
        __builtin_amdgcn_s_barrier();
    };

    for (int t = 0; t < T_; t += 4) {
        step(t + 0, g0);
        step(t + 1, g1);
        step(t + 2, g2);
        step(t + 3, g3);
    }
}

// One wave per sample: a = h2·W1[reg] + b1[reg]; SiLU; corr = a·W2[reg] + b2[reg]
__global__ __launch_bounds__(256) void head_k(const float* __restrict__ h2,
                                              const float* __restrict__ x,
                                              const int* __restrict__ regime,
                                              const float* __restrict__ W1,
                                              const float* __restrict__ b1,
                                              const float* __restrict__ W2,
                                              const float* __restrict__ b2,
                                              const float* __restrict__ lag_scale,
                                              const float* __restrict__ lag_bias,
                                              float* __restrict__ out)
{
    __shared__ alignas(16) float hrow[4][128];
    const int tid = threadIdx.x;
    const int wv = tid >> 6, lane = tid & 63;
    const size_t s = (size_t)blockIdx.x * 4 + wv;
    const int reg = regime[s];

    if (lane < 32)
        ((float4*)hrow[wv])[lane] = ((const float4*)(h2 + s * H_))[lane];
    __syncthreads();

    float acc = b1[reg * K_ + lane];
    const float* Wp = W1 + (size_t)reg * H_ * K_ + lane;
    const float4* h4p = (const float4*)hrow[wv];
    #pragma unroll
    for (int q = 0; q < 32; ++q) {
        float4 h4 = h4p[q];
        acc += h4.x * Wp[(4 * q + 0) * K_];
        acc += h4.y * Wp[(4 * q + 1) * K_];
        acc += h4.z * Wp[(4 * q + 2) * K_];
        acc += h4.w * Wp[(4 * q + 3) * K_];
    }
    float silu = acc * sigm(acc);
    float v = silu * W2[reg * K_ + lane];
    #pragma unroll
    for (int m = 1; m < 64; m <<= 1) v += __shfl_xor(v, m);
    if (lane == 0) {
        float lag = lag_scale[0] * x[s * F_] + lag_bias[0];
        out[s] = lag + v + b2[reg];
    }
}

extern "C" void kernel_launch(void* const* d_in, const int* in_sizes, int n_in,
                              void* d_out, int out_size, void* d_ws, size_t ws_size,
                              hipStream_t stream) {
    const float* x         = (const float*)d_in[0];
    const int*   regime    = (const int*)d_in[1];
    const float* lag_scale = (const float*)d_in[2];
    const float* lag_bias  = (const float*)d_in[3];
    const float* Wih0      = (const float*)d_in[4];
    const float* Whh0      = (const float*)d_in[5];
    const float* bih0      = (const float*)d_in[6];
    const float* bhh0      = (const float*)d_in[7];
    const float* Wih1      = (const float*)d_in[8];
    const float* Whh1      = (const float*)d_in[9];
    const float* bih1      = (const float*)d_in[10];
    const float* bhh1      = (const float*)d_in[11];
    const float* W1        = (const float*)d_in[12];
    const float* b1        = (const float*)d_in[13];
    const float* W2        = (const float*)d_in[14];
    const float* b2        = (const float*)d_in[15];
    float* out = (float*)d_out;

    const size_t NT = (size_t)B_ * T_;               // 131072
    const size_t need = NT * G3_ * 4 + NT * H_ * 4;  // 256 MiB
    if (ws_size < need) {
        hipMemsetAsync(d_out, 0x7F, (size_t)out_size * 4, stream);
        return;
    }
    float* gi = (float*)d_ws;
    float* hb = gi + NT * G3_;                       // h1, then reused as h2

    const int gblocks = (int)(NT / 128);             // 1024
    gemm_gi_mfma<<<gblocks, 512, 0, stream>>>(x, Wih0, bih0, gi);
    gru_seq<<<B_, 512, 0, stream>>>(gi, Whh0, bhh0, hb);
    gemm_gi_mfma<<<gblocks, 512, 0, stream>>>(hb, Wih1, bih1, gi);
    gru_seq<<<B_, 512, 0, stream>>>(gi, Whh1, bhh1, hb);
    head_k<<<(int)(NT / 4), 256, 0, stream>>>(hb, x, regime, W1, b1, W2, b2,
                                              lag_scale, lag_bias, out);
}

// Round 9
// 947.873 us; speedup vs baseline: 1.3473x; 1.0289x over previous
//
#include <hip/hip_runtime.h>
#include <hip/hip_bf16.h>
#include <cstdint>

#define B_ 256
#define T_ 512
#define F_ 128
#define H_ 128
#define G3_ 384
#define R_ 8
#define K_ 64

typedef __attribute__((ext_vector_type(8))) short short8_t;
typedef __attribute__((ext_vector_type(4))) float f32x4;
typedef __attribute__((ext_vector_type(2))) float f32x2;

__device__ __forceinline__ float sigm(float x) { return 1.f / (1.f + __expf(-x)); }
__device__ __forceinline__ float tanh_f(float x) { return 1.f - 2.f / (1.f + __expf(2.f * x)); }
// RNE float->bf16 (finite inputs)
__device__ __forceinline__ unsigned short f2bf(float f) {
    uint32_t u = __builtin_bit_cast(uint32_t, f);
    return (unsigned short)((u + 0x7FFFu + ((u >> 16) & 1u)) >> 16);
}
__device__ __forceinline__ short8_t pack8(float4 a, float4 b) {
    short8_t v;
    v[0] = (short)f2bf(a.x); v[1] = (short)f2bf(a.y);
    v[2] = (short)f2bf(a.z); v[3] = (short)f2bf(a.w);
    v[4] = (short)f2bf(b.x); v[5] = (short)f2bf(b.y);
    v[6] = (short)f2bf(b.z); v[7] = (short)f2bf(b.w);
    return v;
}

// Quad-local butterfly adds on the VALU pipe (DPP quad_perm), replacing
// __shfl_xor's ds_bpermute (LDS pipe, ~120cyc serial latency each).
__device__ __forceinline__ float dpp_red2(float x) {
    // x += xor1(x);  quad_perm [1,0,3,2] = 0xB1
    int a = __builtin_amdgcn_mov_dpp(__builtin_bit_cast(int, x), 0xB1, 0xF, 0xF, true);
    x += __builtin_bit_cast(float, a);
    // x += xor2(x);  quad_perm [2,3,0,1] = 0x4E
    int b = __builtin_amdgcn_mov_dpp(__builtin_bit_cast(int, x), 0x4E, 0xF, 0xF, true);
    x += __builtin_bit_cast(float, b);
    return x;
}

// MFMA GEMM: C[m][n] = sum_k A[m][k]*W[n][k] + bias[n], row-major C.
// M = B*T, N = 384. Block = 128 M x 384 N, 8 waves. W fragments (bf16)
// persist in VGPRs. A staged fp32->bf16 in XOR-swizzled LDS. fp32 accum.
__global__ __launch_bounds__(512, 2) void gemm_gi_mfma(const float* __restrict__ A,
                                                       const float* __restrict__ W,
                                                       const float* __restrict__ bias,
                                                       float* __restrict__ C)
{
    __shared__ alignas(16) unsigned short A_lds[128 * 128];  // bf16, swizzled

    const int tid = threadIdx.x;
    const int wv = tid >> 6, lane = tid & 63;
    const int lc = lane & 15, lg = lane >> 4;
    const size_t m0 = (size_t)blockIdx.x * 128;

    short8_t bf[3][4];
    float bi[3];
    #pragma unroll
    for (int u = 0; u < 3; ++u) {
        const int n = 48 * wv + 16 * u + lc;
        bi[u] = bias[n];
        #pragma unroll
        for (int ks = 0; ks < 4; ++ks) {
            const float4* wp = (const float4*)(W + (size_t)n * 128 + ks * 32 + lg * 8);
            bf[u][ks] = pack8(wp[0], wp[1]);
        }
    }

    {
        const int m = tid >> 2, kq = tid & 3;
        const float4* ap = (const float4*)(A + (m0 + m) * 128 + kq * 32);
        float4 v0 = ap[0], v1 = ap[1], v2 = ap[2], v3 = ap[3];
        float4 v4 = ap[4], v5 = ap[5], v6 = ap[6], v7 = ap[7];
        char* base = (char*)A_lds;
        const int bb = m * 256 + kq * 64, sw = (m & 7) << 4;
        *(short8_t*)(base + ((bb +  0) ^ sw)) = pack8(v0, v1);
        *(short8_t*)(base + ((bb + 16) ^ sw)) = pack8(v2, v3);
        *(short8_t*)(base + ((bb + 32) ^ sw)) = pack8(v4, v5);
        *(short8_t*)(base + ((bb + 48) ^ sw)) = pack8(v6, v7);
    }
    __syncthreads();

    const char* Ab = (const char*)A_lds;
    #pragma unroll 2
    for (int mt = 0; mt < 8; ++mt) {
        short8_t af0 = *(const short8_t*)(Ab + (((mt * 16 + lc) * 256 +  0 + lg * 16) ^ ((lc & 7) << 4)));
        short8_t af1 = *(const short8_t*)(Ab + (((mt * 16 + lc) * 256 + 64 + lg * 16) ^ ((lc & 7) << 4)));
        short8_t af2 = *(const short8_t*)(Ab + (((mt * 16 + lc) * 256 + 128 + lg * 16) ^ ((lc & 7) << 4)));
        short8_t af3 = *(const short8_t*)(Ab + (((mt * 16 + lc) * 256 + 192 + lg * 16) ^ ((lc & 7) << 4)));
        f32x4 a0 = {0.f, 0.f, 0.f, 0.f}, a1 = a0, a2 = a0;
        a0 = __builtin_amdgcn_mfma_f32_16x16x32_bf16(af0, bf[0][0], a0, 0, 0, 0);
        a1 = __builtin_amdgcn_mfma_f32_16x16x32_bf16(af0, bf[1][0], a1, 0, 0, 0);
        a2 = __builtin_amdgcn_mfma_f32_16x16x32_bf16(af0, bf[2][0], a2, 0, 0, 0);
        a0 = __builtin_amdgcn_mfma_f32_16x16x32_bf16(af1, bf[0][1], a0, 0, 0, 0);
        a1 = __builtin_amdgcn_mfma_f32_16x16x32_bf16(af1, bf[1][1], a1, 0, 0, 0);
        a2 = __builtin_amdgcn_mfma_f32_16x16x32_bf16(af1, bf[2][1], a2, 0, 0, 0);
        a0 = __builtin_amdgcn_mfma_f32_16x16x32_bf16(af2, bf[0][2], a0, 0, 0, 0);
        a1 = __builtin_amdgcn_mfma_f32_16x16x32_bf16(af2, bf[1][2], a1, 0, 0, 0);
        a2 = __builtin_amdgcn_mfma_f32_16x16x32_bf16(af2, bf[2][2], a2, 0, 0, 0);
        a0 = __builtin_amdgcn_mfma_f32_16x16x32_bf16(af3, bf[0][3], a0, 0, 0, 0);
        a1 = __builtin_amdgcn_mfma_f32_16x16x32_bf16(af3, bf[1][3], a1, 0, 0, 0);
        a2 = __builtin_amdgcn_mfma_f32_16x16x32_bf16(af3, bf[2][3], a2, 0, 0, 0);
        #pragma unroll
        for (int r = 0; r < 4; ++r) {
            float* cp = C + (m0 + mt * 16 + 4 * lg + r) * G3_ + 48 * wv + lc;
            cp[0]  = a0[r] + bi[0];
            cp[16] = a1[r] + bi[1];
            cp[32] = a2[r] + bi[2];
        }
    }
}

// One block (512 threads, 8 waves) per batch element.
// Thread: j = 16*(tid>>6) + (lane>>2); k-chunk s = lane&3 covers [32s,32s+32).
// Matvec as f32x2 packed ops; reduce over the 4 k-chunks with DPP quad-perm
// adds (VALU pipe — replaces ds_bpermute LDS round-trips). h double-buffered
// in LDS [4][36]. gi prefetched FOUR steps ahead. ONE raw s_barrier per
// step, lgkm-only drain (hout stores + gi prefetch stay in flight).
__global__ __launch_bounds__(512, 2) void gru_seq(const float* __restrict__ gi,
                                                  const float* __restrict__ Whh,
                                                  const float* __restrict__ bhh,
                                                  float* __restrict__ hout)
{
    __shared__ alignas(16) float hbuf[2][4][36];

    const int tid = threadIdx.x;
    const int b = blockIdx.x;
    const int w = tid >> 6, lane = tid & 63;
    const int j = 16 * w + (lane >> 2);
    const int s = lane & 3;
    const bool fin = (s == 0);

    // per-thread weights as fp32 PAIRS: rows j, 128+j, 256+j; cols [32s,32s+32)
    f32x2 wr2[16], wz2[16], wn2[16];
    {
        const float4* p0 = (const float4*)(Whh + (size_t)j * 128 + s * 32);
        const float4* p1 = (const float4*)(Whh + (size_t)(128 + j) * 128 + s * 32);
        const float4* p2 = (const float4*)(Whh + (size_t)(256 + j) * 128 + s * 32);
        #pragma unroll
        for (int q = 0; q < 8; ++q) {
            float4 v0 = p0[q], v1 = p1[q], v2 = p2[q];
            wr2[2*q]   = f32x2{v0.x, v0.y};
            wr2[2*q+1] = f32x2{v0.z, v0.w};
            wz2[2*q]   = f32x2{v1.x, v1.y};
            wz2[2*q+1] = f32x2{v1.z, v1.w};
            wn2[2*q]   = f32x2{v2.x, v2.y};
            wn2[2*q+1] = f32x2{v2.z, v2.w};
        }
    }
    const float br = bhh[j], bz = bhh[128 + j], bn = bhh[256 + j];

    if (tid < H_) hbuf[0][tid >> 5][tid & 31] = 0.f;
    __syncthreads();

    const float* gip = gi + (size_t)b * T_ * G3_ + j;
    float* hop = hout + (size_t)b * T_ * H_ + j;

    // 4-deep gi prefetch (finalize lanes only), named sets for static indexing
    float g0[3], g1[3], g2[3], g3[3];
    if (fin) {
        #pragma unroll
        for (int u = 0; u < 3; ++u) {
            g0[u] = gip[0 * G3_ + 128 * u];
            g1[u] = gip[1 * G3_ + 128 * u];
            g2[u] = gip[2 * G3_ + 128 * u];
            g3[u] = gip[3 * G3_ + 128 * u];
        }
    }
    float hprev = 0.f;

    auto step = [&](int t, float (&gc)[3]) {
        const int p = t & 1;
        const float4* hv = (const float4*)(&hbuf[p][s][0]);
        f32x2 pr2 = {0.f, 0.f}, pz2 = pr2, pn2 = pr2;
        #pragma unroll
        for (int q = 0; q < 8; ++q) {
            float4 h4 = hv[q];
            f32x2 ha = {h4.x, h4.y};
            f32x2 hb = {h4.z, h4.w};
            pr2 += wr2[2*q] * ha;  pr2 += wr2[2*q+1] * hb;
            pz2 += wz2[2*q] * ha;  pz2 += wz2[2*q+1] * hb;
            pn2 += wn2[2*q] * ha;  pn2 += wn2[2*q+1] * hb;
        }
        // reduce over 4 k-chunks: DPP quad-perm butterflies (VALU pipe)
        float pr = dpp_red2(pr2[0] + pr2[1]);
        float pz = dpp_red2(pz2[0] + pz2[1]);
        float pn = dpp_red2(pn2[0] + pn2[1]);

        if (fin) {
            float r  = sigm(gc[0] + pr + br);
            float z  = sigm(gc[1] + pz + bz);
            float nn = tanh_f(gc[2] + r * (pn + bn));
            float h  = (1.f - z) * nn + z * hprev;
            hprev = h;
            hbuf[p ^ 1][j >> 5][j & 31] = h;
            hop[(size_t)t * H_] = h;                     // fire-and-forget
            // refill this set for t+4
            int tn = (t + 4 < T_) ? t + 4 : T_ - 1;
            const float* gp = gip + (size_t)tn * G3_;
            gc[0] = gp[0]; gc[1] = gp[128]; gc[2] = gp[256];
        }
        // LDS-only drain + raw barrier (global ops stay in flight)
        asm volatile("s_waitcnt lgkmcnt(0)" ::: "memory");
        __builtin_amdgcn_s_barrier();
    };

    for (int t = 0; t < T_; t += 4) {
        step(t + 0, g0);
        step(t + 1, g1);
        step(t + 2, g2);
        step(t + 3, g3);
    }
}

// One wave per sample: a = h2·W1[reg] + b1[reg]; SiLU; corr = a·W2[reg] + b2[reg]
__global__ __launch_bounds__(256) void head_k(const float* __restrict__ h2,
                                              const float* __restrict__ x,
                                              const int* __restrict__ regime,
                                              const float* __restrict__ W1,
                                              const float* __restrict__ b1,
                                              const float* __restrict__ W2,
                                              const float* __restrict__ b2,
                                              const float* __restrict__ lag_scale,
                                              const float* __restrict__ lag_bias,
                                              float* __restrict__ out)
{
    __shared__ alignas(16) float hrow[4][128];
    const int tid = threadIdx.x;
    const int wv = tid >> 6, lane = tid & 63;
    const size_t s = (size_t)blockIdx.x * 4 + wv;
    const int reg = regime[s];

    if (lane < 32)
        ((float4*)hrow[wv])[lane] = ((const float4*)(h2 + s * H_))[lane];
    __syncthreads();

    float acc = b1[reg * K_ + lane];
    const float* Wp = W1 + (size_t)reg * H_ * K_ + lane;
    const float4* h4p = (const float4*)hrow[wv];
    #pragma unroll
    for (int q = 0; q < 32; ++q) {
        float4 h4 = h4p[q];
        acc += h4.x * Wp[(4 * q + 0) * K_];
        acc += h4.y * Wp[(4 * q + 1) * K_];
        acc += h4.z * Wp[(4 * q + 2) * K_];
        acc += h4.w * Wp[(4 * q + 3) * K_];
    }
    float silu = acc * sigm(acc);
    float v = silu * W2[reg * K_ + lane];
    #pragma unroll
    for (int m = 1; m < 64; m <<= 1) v += __shfl_xor(v, m);
    if (lane == 0) {
        float lag = lag_scale[0] * x[s * F_] + lag_bias[0];
        out[s] = lag + v + b2[reg];
    }
}

extern "C" void kernel_launch(void* const* d_in, const int* in_sizes, int n_in,
                              void* d_out, int out_size, void* d_ws, size_t ws_size,
                              hipStream_t stream) {
    const float* x         = (const float*)d_in[0];
    const int*   regime    = (const int*)d_in[1];
    const float* lag_scale = (const float*)d_in[2];
    const float* lag_bias  = (const float*)d_in[3];
    const float* Wih0      = (const float*)d_in[4];
    const float* Whh0      = (const float*)d_in[5];
    const float* bih0      = (const float*)d_in[6];
    const float* bhh0      = (const float*)d_in[7];
    const float* Wih1      = (const float*)d_in[8];
    const float* Whh1      = (const float*)d_in[9];
    const float* bih1      = (const float*)d_in[10];
    const float* bhh1      = (const float*)d_in[11];
    const float* W1        = (const float*)d_in[12];
    const float* b1        = (const float*)d_in[13];
    const float* W2        = (const float*)d_in[14];
    const float* b2        = (const float*)d_in[15];
    float* out = (float*)d_out;

    const size_t NT = (size_t)B_ * T_;               // 131072
    const size_t need = NT * G3_ * 4 + NT * H_ * 4;  // 256 MiB
    if (ws_size < need) {
        hipMemsetAsync(d_out, 0x7F, (size_t)out_size * 4, stream);
        return;
    }
    float* gi = (float*)d_ws;
    float* hb = gi + NT * G3_;                       // h1, then reused as h2

    const int gblocks = (int)(NT / 128);             // 1024
    gemm_gi_mfma<<<gblocks, 512, 0, stream>>>(x, Wih0, bih0, gi);
    gru_seq<<<B_, 512, 0, stream>>>(gi, Whh0, bhh0, hb);
    gemm_gi_mfma<<<gblocks, 512, 0, stream>>>(hb, Wih1, bih1, gi);
    gru_seq<<<B_, 512, 0, stream>>>(gi, Whh1, bhh1, hb);
    head_k<<<(int)(NT / 4), 256, 0, stream>>>(hb, x, regime, W1, b1, W2, b2,
                                              lag_scale, lag_bias, out);
}